// Round 6
// baseline (69338.336 us; speedup 1.0000x reference)
//
#include <hip/hip_runtime.h>
#include <math.h>

// ---------------------------------------------------------------------------
// PhyRNN: 2-layer LSTM (B=64, T=3000, I=8, H=128) + FC head + double FD deriv.
//
// R6. History:
//  R1 16.6 ms: 512thr w[128]/thread > 128-VGPR cap -> spill.
//  R2 36.5 ms: waves_per_eu(2,2) ignored; 6 GB scratch storm.
//  R3 18.6 ms: 1024thr w[64]/thread but LDS small -> allocator chased
//              8 waves/SIMD -> 52/64 VGPRs -> weights remat'd from L2.
//  R4 27.2 ms: 512thr w[2][64] demand 190 > 128 cap -> remat again.
//  R5: no data (container failed; only unknown was 149 KB LDS).
//  MODEL: allocator picks VGPRs to hit the max occupancy ALLOWED BY LDS.
//  R6: 1024thr (16 waves), LDS clamp 85 KB -> 1 block/CU is the LDS max ->
//      4 waves/SIMD -> any VGPR<=128 is occupancy-equivalent -> w[64]+~35
//      temps (~100) stays resident. All weights in VGPRs, no LDS streaming.
//      Layer1: input-proj K-half accumulated into acc[CHUNK=10] REGISTERS
//      (W_ih streamed k-outer from L2, 16 loads/chunk); the end-of-step
//      shfl_xor(1) K-half combine also sums the xp halves. Phase B fully
//      unrolled (static acc[tt] indexing). One barrier/step.
//
// Thread map (verified correct in R3): tid = j*8 + sub, sub = gt*2 + hf.
// gt: 0=i 1=f 2=g 3=o (PyTorch order); hf = K-half. Row r = gt*128 + j.
// Combine: accs += shfl_xor(accs,1); av act; t1=shfl2(av) t2=shfl4(av)
// t3=shfl4(t1); sub==0: c = t1*c + av*t2; h = t3*tanh(c).
//
// Precision: fp32 (no fp32 MFMA on CDNA4; double FD deriv amplifies noise).
// ws: h buffer 98.304 MB + y 0.768 MB + z 0.768 MB (proven fit).
// ---------------------------------------------------------------------------

#define T_STEPS 3000
#define BATCH   64
#define HID     128
#define CHUNK   10      // 3000 = 300*10
#define INV_DT  50.0f   // 1/0.02

__device__ __forceinline__ float sigmoid_(float x) {
    return 1.0f / (1.0f + __expf(-x));
}
__device__ __forceinline__ float tanh_(float x) {
    return 1.0f - 2.0f / (__expf(2.0f * x) + 1.0f);
}

// Occupancy clamp: >80 KB LDS -> 1 block/CU -> 4 waves/SIMD -> 128-VGPR
// budget with nothing to gain from spilling below it.
#define LDS_CLAMP(guard_cond, sink)                     \
    __shared__ float pad0[21504]; /* 84 KB */           \
    if (guard_cond) {             /* never true */      \
        pad0[threadIdx.x] = (float)threadIdx.x;         \
        ((volatile float*)(sink))[0] = pad0[threadIdx.x ^ 1]; \
    }

// ---------------------------------------------------------------- layer 0 ---
__global__ void __launch_bounds__(1024, 4)
lstm_layer0(const float* __restrict__ x,      // [64][3000][8]
            const float* __restrict__ w_ih,   // [512][8]
            const float* __restrict__ w_hh,   // [512][128]
            const float* __restrict__ b_ih,
            const float* __restrict__ b_hh,
            float* __restrict__ h_out)        // [64][3000][128]
{
    const int b   = blockIdx.x;
    const int tid = threadIdx.x;
    const int j   = tid >> 3;            // hidden unit 0..127
    const int sub = tid & 7;
    const int gt  = sub >> 1;            // 0=i 1=f 2=g 3=o
    const int hf  = sub & 1;             // K-half
    const int r   = gt * HID + j;
    const int kb  = hf * 64;

    __shared__ __align__(16) float h_s[2][HID];
    LDS_CLAMP(b == 0x7fffffff, h_s)

    float w[64];                         // W_hh half-row, VGPR-resident
#pragma unroll
    for (int i = 0; i < 64; i += 4) {
        float4 v = *(const float4*)(w_hh + (size_t)r * HID + kb + i);
        w[i] = v.x; w[i+1] = v.y; w[i+2] = v.z; w[i+3] = v.w;
    }
    float wi[8];
#pragma unroll
    for (int i = 0; i < 8; i += 4) {
        float4 v = *(const float4*)(w_ih + (size_t)r * 8 + i);
        wi[i] = v.x; wi[i+1] = v.y; wi[i+2] = v.z; wi[i+3] = v.w;
    }
    const float bias = b_ih[r] + b_hh[r];
    float c = 0.0f;                      // valid in sub==0 lanes

    if (tid < HID) h_s[0][tid] = 0.0f;
    __syncthreads();

    const float* xrow = x + (size_t)b * T_STEPS * 8;
    float* hb = h_out + (size_t)b * T_STEPS * HID;

#pragma unroll 1
    for (int t = 0; t < T_STEPS; ++t) {
        const int rb = t & 1;
        float4 xa = *(const float4*)(xrow + t * 8);
        float4 xc = *(const float4*)(xrow + t * 8 + 4);
        float xterm = bias
                    + wi[0]*xa.x + wi[1]*xa.y + wi[2]*xa.z + wi[3]*xa.w
                    + wi[4]*xc.x + wi[5]*xc.y + wi[6]*xc.z + wi[7]*xc.w;
        float acc0 = hf ? 0.0f : xterm;  // bias + x-term counted once
        float acc1 = 0.f, acc2 = 0.f, acc3 = 0.f;
#pragma unroll
        for (int k4 = 0; k4 < 16; k4 += 4) {
            float4 h0 = *(const float4*)(&h_s[rb][kb + 4*k4]);
            float4 h1 = *(const float4*)(&h_s[rb][kb + 4*k4 + 4]);
            float4 h2 = *(const float4*)(&h_s[rb][kb + 4*k4 + 8]);
            float4 h3 = *(const float4*)(&h_s[rb][kb + 4*k4 + 12]);
            acc0 += w[4*k4   ]*h0.x + w[4*k4+ 1]*h0.y + w[4*k4+ 2]*h0.z + w[4*k4+ 3]*h0.w;
            acc1 += w[4*k4+ 4]*h1.x + w[4*k4+ 5]*h1.y + w[4*k4+ 6]*h1.z + w[4*k4+ 7]*h1.w;
            acc2 += w[4*k4+ 8]*h2.x + w[4*k4+ 9]*h2.y + w[4*k4+10]*h2.z + w[4*k4+11]*h2.w;
            acc3 += w[4*k4+12]*h3.x + w[4*k4+13]*h3.y + w[4*k4+14]*h3.z + w[4*k4+15]*h3.w;
        }
        float accs = (acc0 + acc1) + (acc2 + acc3);
        accs += __shfl_xor(accs, 1);     // combine K-halves

        float av = (gt == 2) ? tanh_(accs) : sigmoid_(accs);
        float t1 = __shfl_xor(av, 2);
        float t2 = __shfl_xor(av, 4);
        float t3 = __shfl_xor(t1, 4);
        if (sub == 0) {                  // av=sig_i t1=sig_f t2=tanh_g t3=sig_o
            c = t1 * c + av * t2;
            float h = t3 * tanh_(c);
            h_s[rb ^ 1][j] = h;
            hb[(size_t)t * HID + j] = h;
        }
        __syncthreads();
    }
}

// ---------------------------------------------------------------- layer 1 ---
__global__ void __launch_bounds__(1024, 4)
lstm_layer1(const float* __restrict__ w_ih,   // [512][128]
            const float* __restrict__ w_hh,   // [512][128]
            const float* __restrict__ b_ih,
            const float* __restrict__ b_hh,
            float* __restrict__ h_buf)        // in: h1, out: h2 (in place)
{
    const int b   = blockIdx.x;
    const int tid = threadIdx.x;
    const int j   = tid >> 3;
    const int sub = tid & 7;
    const int gt  = sub >> 1;
    const int hf  = sub & 1;
    const int r   = gt * HID + j;
    const int kb  = hf * 64;

    __shared__ __align__(16) float h_s[2][HID];
    LDS_CLAMP(b == 0x7fffffff, h_s)

    float w[64];                         // W_hh half-row, resident all kernel
#pragma unroll
    for (int i = 0; i < 64; i += 4) {
        float4 v = *(const float4*)(w_hh + (size_t)r * HID + kb + i);
        w[i] = v.x; w[i+1] = v.y; w[i+2] = v.z; w[i+3] = v.w;
    }
    const float bias = b_ih[r] + b_hh[r];
    float c = 0.0f;
    if (tid < HID) h_s[0][tid] = 0.0f;
    __syncthreads();

    float* hbB = h_buf + (size_t)b * T_STEPS * HID;
    const float* wihr = w_ih + (size_t)r * HID + kb;   // own W_ih half-row

    for (int t0 = 0; t0 < T_STEPS; t0 += CHUNK) {
        // ---- phase A: half input-projection into REGISTERS.
        // acc[tau] = (hf?0:bias) + W_ih[r][kb..kb+64) . h1[t0+tau][kb..kb+64)
        // W_ih streamed k-outer from L2 (16 loads/chunk); h1 loads are
        // 2-address-per-wave (L1-hot, 5 KB/chunk working set).
        float acc[CHUNK];
#pragma unroll
        for (int tau = 0; tau < CHUNK; ++tau) acc[tau] = hf ? 0.0f : bias;
        const float* hp = hbB + (size_t)t0 * HID + kb;
#pragma unroll
        for (int k4 = 0; k4 < 16; ++k4) {
            float4 w4 = *(const float4*)(wihr + 4 * k4);
#pragma unroll
            for (int tau = 0; tau < CHUNK; ++tau) {
                float4 h4 = *(const float4*)(hp + tau * HID + 4 * k4);
                acc[tau] += w4.x*h4.x + w4.y*h4.y + w4.z*h4.z + w4.w*h4.w;
            }
        }
        __syncthreads();   // all h1 chunk reads done before h2 writes below

        // ---- phase B: serial recurrence (fully unrolled: acc[tt] static)
#pragma unroll
        for (int tt = 0; tt < CHUNK; ++tt) {
            const int rb = tt & 1;       // t0 even -> (t0+tt)&1 == tt&1
            float a0 = acc[tt];
            float a1 = 0.f, a2 = 0.f, a3 = 0.f;
#pragma unroll
            for (int k4 = 0; k4 < 16; k4 += 4) {
                float4 h0 = *(const float4*)(&h_s[rb][kb + 4*k4]);
                float4 h1 = *(const float4*)(&h_s[rb][kb + 4*k4 + 4]);
                float4 h2 = *(const float4*)(&h_s[rb][kb + 4*k4 + 8]);
                float4 h3 = *(const float4*)(&h_s[rb][kb + 4*k4 + 12]);
                a0 += w[4*k4   ]*h0.x + w[4*k4+ 1]*h0.y + w[4*k4+ 2]*h0.z + w[4*k4+ 3]*h0.w;
                a1 += w[4*k4+ 4]*h1.x + w[4*k4+ 5]*h1.y + w[4*k4+ 6]*h1.z + w[4*k4+ 7]*h1.w;
                a2 += w[4*k4+ 8]*h2.x + w[4*k4+ 9]*h2.y + w[4*k4+10]*h2.z + w[4*k4+11]*h2.w;
                a3 += w[4*k4+12]*h3.x + w[4*k4+13]*h3.y + w[4*k4+14]*h3.z + w[4*k4+15]*h3.w;
            }
            float accs = (a0 + a1) + (a2 + a3);
            accs += __shfl_xor(accs, 1);     // K-halves AND xp halves combine

            float av = (gt == 2) ? tanh_(accs) : sigmoid_(accs);
            float t1 = __shfl_xor(av, 2);
            float t2 = __shfl_xor(av, 4);
            float t3 = __shfl_xor(t1, 4);
            if (sub == 0) {
                c = t1 * c + av * t2;
                float h = t3 * tanh_(c);
                h_s[rb ^ 1][j] = h;
                hbB[(size_t)(t0 + tt) * HID + j] = h;   // h2 overwrites h1
            }
            __syncthreads();
        }
    }
}

// ---------------------------------------------------------------- FC head ---
__global__ void __launch_bounds__(256)
fc_head(const float* __restrict__ h_buf,  // h2 [64][3000][128]
        const float* __restrict__ fc1_w, const float* __restrict__ fc1_b,
        const float* __restrict__ fc2_w, const float* __restrict__ fc2_b,
        const float* __restrict__ fc3_w, const float* __restrict__ fc3_b,
        float* __restrict__ y_bt)         // [64][3000]
{
    __shared__ __align__(16) float w1[16 * HID];   // 8 KB
    __shared__ float sb[89];
    const int tid = threadIdx.x;
    for (int i = tid; i < 16 * HID; i += 256) w1[i] = fc1_w[i];
    if (tid < 16) sb[tid]      = fc1_b[tid];
    if (tid < 64) sb[16 + tid] = fc2_w[tid];
    if (tid < 4)  sb[80 + tid] = fc2_b[tid];
    if (tid < 4)  sb[84 + tid] = fc3_w[tid];
    if (tid == 0) sb[88]       = fc3_b[0];
    __syncthreads();

    const int idx = blockIdx.x * 256 + tid;        // b*3000 + t
    if (idx >= BATCH * T_STEPS) return;
    const float* h = h_buf + (size_t)idx * HID;

    float y1[16];
#pragma unroll
    for (int jo = 0; jo < 16; ++jo) y1[jo] = sb[jo];
#pragma unroll 4
    for (int k4 = 0; k4 < 32; ++k4) {
        float4 hv = *(const float4*)(h + 4 * k4);
#pragma unroll
        for (int jo = 0; jo < 16; ++jo) {
            float4 wv = *(const float4*)(&w1[jo * HID + 4 * k4]);
            y1[jo] += wv.x*hv.x + wv.y*hv.y + wv.z*hv.z + wv.w*hv.w;
        }
    }
    float y2[4];
#pragma unroll
    for (int jo = 0; jo < 4; ++jo) {
        float a = sb[80 + jo];
#pragma unroll
        for (int k = 0; k < 16; ++k) a += sb[16 + jo * 16 + k] * fmaxf(y1[k], 0.0f);
        y2[jo] = fmaxf(a, 0.0f);
    }
    float y = sb[88];
#pragma unroll
    for (int k = 0; k < 4; ++k) y += sb[84 + k] * y2[k];

    y_bt[idx] = y;   // coalesced (t fast)
}

// ------------------------------------------------------------- FD stencil ---
// phi row 0: (-1.5,2,-0.5)/dt ; rows 1..n-2: (-0.5,0,0.5)/dt ;
// row n-1: (0.5,-2,1.5)/dt.  Applied twice = exact phi@(phi@y).
__global__ void deriv_k(const float* __restrict__ in,   // [64][3000]
                        float* __restrict__ outp)       // [64][3000]
{
    const int idx = blockIdx.x * blockDim.x + threadIdx.x;
    if (idx >= BATCH * T_STEPS) return;
    const int t = idx % T_STEPS;
    float v;
    if (t == 0) {
        v = (-1.5f * in[idx] + 2.0f * in[idx + 1] - 0.5f * in[idx + 2]) * INV_DT;
    } else if (t == T_STEPS - 1) {
        v = (0.5f * in[idx - 2] - 2.0f * in[idx - 1] + 1.5f * in[idx]) * INV_DT;
    } else {
        v = (in[idx + 1] - in[idx - 1]) * (0.5f * INV_DT);
    }
    outp[idx] = v;
}

// ------------------------------------------------------------------ launch --
extern "C" void kernel_launch(void* const* d_in, const int* in_sizes, int n_in,
                              void* d_out, int out_size, void* d_ws, size_t ws_size,
                              hipStream_t stream)
{
    const float* x     = (const float*)d_in[0];
    const float* w_ih0 = (const float*)d_in[1];
    const float* w_hh0 = (const float*)d_in[2];
    const float* b_ih0 = (const float*)d_in[3];
    const float* b_hh0 = (const float*)d_in[4];
    const float* w_ih1 = (const float*)d_in[5];
    const float* w_hh1 = (const float*)d_in[6];
    const float* b_ih1 = (const float*)d_in[7];
    const float* b_hh1 = (const float*)d_in[8];
    const float* fc1_w = (const float*)d_in[9];
    const float* fc1_b = (const float*)d_in[10];
    const float* fc2_w = (const float*)d_in[11];
    const float* fc2_b = (const float*)d_in[12];
    const float* fc3_w = (const float*)d_in[13];
    const float* fc3_b = (const float*)d_in[14];
    float* out = (float*)d_out;

    // ws layout: h buffer (98.304 MB) | y (0.768 MB) | z (0.768 MB)
    float* h_buf = (float*)d_ws;
    float* y_bt  = (float*)((char*)d_ws + 98304000);
    float* z_bt  = (float*)((char*)d_ws + 98304000 + 768000);

    lstm_layer0<<<dim3(BATCH), dim3(1024), 0, stream>>>(x, w_ih0, w_hh0, b_ih0, b_hh0, h_buf);
    lstm_layer1<<<dim3(BATCH), dim3(1024), 0, stream>>>(w_ih1, w_hh1, b_ih1, b_hh1, h_buf);

    const int nelem = T_STEPS * BATCH;   // 192000 = 750 * 256
    fc_head<<<dim3(nelem / 256), dim3(256), 0, stream>>>(
        h_buf, fc1_w, fc1_b, fc2_w, fc2_b, fc3_w, fc3_b, y_bt);
    deriv_k<<<dim3(nelem / 256), dim3(256), 0, stream>>>(y_bt, z_bt);
    deriv_k<<<dim3(nelem / 256), dim3(256), 0, stream>>>(z_bt, out);
}

// Round 7
// 15689.056 us; speedup vs baseline: 4.4195x; 4.4195x over previous
//
#include <hip/hip_runtime.h>
#include <math.h>

// ---------------------------------------------------------------------------
// PhyRNN: 2-layer LSTM (B=64, T=3000, I=8, H=128) + FC head + double FD deriv.
//
// R7. History:
//  R1 16.6 ms: 512thr w[128]/thread, VGPR cap 128 -> spill.
//  R2 36.5 ms: waves_per_eu(2,2) IGNORED; 6 GB scratch storm.
//  R3 18.6 ms: 1024thr -> allocator gave 52/64 VGPRs, remat from L2.
//  R4 27.2 ms: 512thr, LDS-capped occupancy didn't raise budget; 128 again.
//  R5 no data: container failed (149 KB LDS untested; likely infra).
//  R6 69.3 ms: 1024thr + LDS clamp -> VGPR=64 anyway; 72 GB scratch storm.
//  ALLOCATOR MODEL (6 rounds of evidence): VGPR target is set by thread
//  count alone: 512thr -> 128, 1024thr -> 64. No attribute changes it.
//  R7 = R5 hardened: design INSIDE 128 VGPRs. 512 thr, one gate row per
//  thread (tid=j*4+gt, proven R1/R4): K-half [0,64) in VGPRs (w[64]),
//  K-half [64,128) in LDS (Wl, 128 KB, XOR-rotated rows -> all-32-bank
//  spread for ds_read_b128). h reads are wave-uniform broadcasts.
//  Layer1: input projection accumulated into acc[CHUNK=10] REGISTERS
//  (no xp LDS); phase B consumes acc[tt] statically. LDS 132 KB (<149).
//
// Precision: fp32 (no fp32 MFMA on CDNA4; double FD deriv amplifies noise).
// ws: h buffer 98.304 MB + y 0.768 MB + z 0.768 MB (proven fit).
// ---------------------------------------------------------------------------

#define T_STEPS 3000
#define BATCH   64
#define HID     128
#define CHUNK   10      // 3000 = 300*10
#define INV_DT  50.0f   // 1/0.02

__device__ __forceinline__ float sigmoid_(float x) {
    return 1.0f / (1.0f + __expf(-x));
}
__device__ __forceinline__ float tanh_(float x) {
    return 1.0f - 2.0f / (__expf(2.0f * x) + 1.0f);
}

// ---------------------------------------------------------------- layer 0 ---
// 64 blocks (1/batch), 512 threads. tid = j*4 + gt; row r = gt*128 + j.
__global__ void __launch_bounds__(512)
lstm_layer0(const float* __restrict__ x,      // [64][3000][8]
            const float* __restrict__ w_ih,   // [512][8]
            const float* __restrict__ w_hh,   // [512][128]
            const float* __restrict__ b_ih,
            const float* __restrict__ b_hh,
            float* __restrict__ h_out)        // [64][3000][128]
{
    const int b   = blockIdx.x;
    const int tid = threadIdx.x;
    const int j   = tid >> 2;            // hidden unit
    const int gt  = tid & 3;             // 0=i 1=f 2=g 3=o (PyTorch order)
    const int r   = gt * HID + j;
    const int rot = (tid & 7) << 2;      // bank-spreading rotation (mult of 4)

    __shared__ __align__(16) float Wl[512 * 64];     // 128 KB: K in [64,128)
    __shared__ __align__(16) float h_s[2][HID];      // 1 KB

    // lower K-half -> VGPRs (one-time)
    float w[64];
#pragma unroll
    for (int i = 0; i < 64; i += 4) {
        float4 v = *(const float4*)(w_hh + (size_t)r * HID + i);
        w[i] = v.x; w[i+1] = v.y; w[i+2] = v.z; w[i+3] = v.w;
    }
    // upper K-half -> LDS, XOR-rotated float4 units (one-time, bijective)
#pragma unroll
    for (int i = 0; i < 64; i += 4) {
        float4 v = *(const float4*)(w_hh + (size_t)r * HID + 64 + i);
        *(float4*)&Wl[tid * 64 + (i ^ rot)] = v;
    }
    float wi[8];
#pragma unroll
    for (int i = 0; i < 8; i += 4) {
        float4 v = *(const float4*)(w_ih + (size_t)r * 8 + i);
        wi[i] = v.x; wi[i+1] = v.y; wi[i+2] = v.z; wi[i+3] = v.w;
    }
    const float bias = b_ih[r] + b_hh[r];
    float c = 0.0f;                      // valid in gt==0 lanes

    if (tid < HID) h_s[0][tid] = 0.0f;
    __syncthreads();

    const float* xrow = x + (size_t)b * T_STEPS * 8;
    float* hb = h_out + (size_t)b * T_STEPS * HID;

#pragma unroll 1
    for (int t = 0; t < T_STEPS; ++t) {
        const int rb = t & 1;
        float4 xa = *(const float4*)(xrow + t * 8);
        float4 xc = *(const float4*)(xrow + t * 8 + 4);
        float a0 = bias
                 + wi[0]*xa.x + wi[1]*xa.y + wi[2]*xa.z + wi[3]*xa.w
                 + wi[4]*xc.x + wi[5]*xc.y + wi[6]*xc.z + wi[7]*xc.w;
        float a1 = 0.f, a2 = 0.f, a3 = 0.f;
        float b0 = 0.f, b1 = 0.f, b2 = 0.f, b3 = 0.f;

        // lower half: VGPR weights, h broadcast (wave-uniform addresses)
#pragma unroll
        for (int k4 = 0; k4 < 16; k4 += 4) {
            float4 h0 = *(const float4*)(&h_s[rb][4*k4]);
            float4 h1 = *(const float4*)(&h_s[rb][4*k4 + 4]);
            float4 h2 = *(const float4*)(&h_s[rb][4*k4 + 8]);
            float4 h3 = *(const float4*)(&h_s[rb][4*k4 + 12]);
            a0 += w[4*k4   ]*h0.x + w[4*k4+ 1]*h0.y + w[4*k4+ 2]*h0.z + w[4*k4+ 3]*h0.w;
            a1 += w[4*k4+ 4]*h1.x + w[4*k4+ 5]*h1.y + w[4*k4+ 6]*h1.z + w[4*k4+ 7]*h1.w;
            a2 += w[4*k4+ 8]*h2.x + w[4*k4+ 9]*h2.y + w[4*k4+10]*h2.z + w[4*k4+11]*h2.w;
            a3 += w[4*k4+12]*h3.x + w[4*k4+13]*h3.y + w[4*k4+14]*h3.z + w[4*k4+15]*h3.w;
        }
        // upper half: LDS weights (XOR-rotated rows), h broadcast
        {
            const float* wlp = &Wl[tid * 64];
#pragma unroll
            for (int i = 0; i < 64; i += 16) {
                float4 g0 = *(const float4*)(wlp + ((i     ) ^ rot));
                float4 g1 = *(const float4*)(wlp + ((i +  4) ^ rot));
                float4 g2 = *(const float4*)(wlp + ((i +  8) ^ rot));
                float4 g3 = *(const float4*)(wlp + ((i + 12) ^ rot));
                float4 h0 = *(const float4*)(&h_s[rb][64 + i]);
                float4 h1 = *(const float4*)(&h_s[rb][64 + i + 4]);
                float4 h2 = *(const float4*)(&h_s[rb][64 + i + 8]);
                float4 h3 = *(const float4*)(&h_s[rb][64 + i + 12]);
                b0 += g0.x*h0.x + g0.y*h0.y + g0.z*h0.z + g0.w*h0.w;
                b1 += g1.x*h1.x + g1.y*h1.y + g1.z*h1.z + g1.w*h1.w;
                b2 += g2.x*h2.x + g2.y*h2.y + g2.z*h2.z + g2.w*h2.w;
                b3 += g3.x*h3.x + g3.y*h3.y + g3.z*h3.z + g3.w*h3.w;
            }
        }
        float acc = ((a0 + a1) + (a2 + a3)) + ((b0 + b1) + (b2 + b3));

        float av = (gt == 2) ? tanh_(acc) : sigmoid_(acc);
        float t1 = __shfl_xor(av, 1);
        float t2 = __shfl_xor(av, 2);
        float t3 = __shfl_xor(t1, 2);
        if (gt == 0) {                   // av=sig_i t1=sig_f t2=tanh_g t3=sig_o
            c = t1 * c + av * t2;
            float h = t3 * tanh_(c);
            h_s[rb ^ 1][j] = h;
            hb[(size_t)t * HID + j] = h;
        }
        __syncthreads();
    }
}

// ---------------------------------------------------------------- layer 1 ---
// Per CHUNK=10: phase A accumulates the FULL input projection (K=128) into
// acc[10] registers, W_ih streamed k-outer (per-lane rows, L2-hot), h1 via
// wave-uniform loads. One barrier; phase B serial recurrence (in-place h2).
__global__ void __launch_bounds__(512)
lstm_layer1(const float* __restrict__ w_ih,   // [512][128]
            const float* __restrict__ w_hh,   // [512][128]
            const float* __restrict__ b_ih,
            const float* __restrict__ b_hh,
            float* __restrict__ h_buf)        // in: h1, out: h2 (in place)
{
    const int b   = blockIdx.x;
    const int tid = threadIdx.x;
    const int j   = tid >> 2;
    const int gt  = tid & 3;
    const int r   = gt * HID + j;
    const int rot = (tid & 7) << 2;

    __shared__ __align__(16) float Wl[512 * 64];     // 128 KB
    __shared__ __align__(16) float h_s[2][HID];      // 1 KB (total 129 KB)

    float w[64];
#pragma unroll
    for (int i = 0; i < 64; i += 4) {
        float4 v = *(const float4*)(w_hh + (size_t)r * HID + i);
        w[i] = v.x; w[i+1] = v.y; w[i+2] = v.z; w[i+3] = v.w;
    }
#pragma unroll
    for (int i = 0; i < 64; i += 4) {
        float4 v = *(const float4*)(w_hh + (size_t)r * HID + 64 + i);
        *(float4*)&Wl[tid * 64 + (i ^ rot)] = v;
    }
    const float bias = b_ih[r] + b_hh[r];
    float c = 0.0f;
    if (tid < HID) h_s[0][tid] = 0.0f;
    __syncthreads();

    float* hbB = h_buf + (size_t)b * T_STEPS * HID;
    const float* wihr = w_ih + (size_t)r * HID;

    for (int t0 = 0; t0 < T_STEPS; t0 += CHUNK) {
        // ---- phase A: acc[tau] = bias + W_ih[r] . h1[t0+tau]  (K=128)
        float acc[CHUNK];
#pragma unroll
        for (int tau = 0; tau < CHUNK; ++tau) acc[tau] = bias;
        const float* hp = hbB + (size_t)t0 * HID;
#pragma unroll 2
        for (int k4 = 0; k4 < 32; ++k4) {
            float4 w4 = *(const float4*)(wihr + 4 * k4);   // per-lane row
#pragma unroll
            for (int tau = 0; tau < CHUNK; ++tau) {
                float4 h4 = *(const float4*)(hp + tau * HID + 4 * k4); // uniform
                acc[tau] += w4.x*h4.x + w4.y*h4.y + w4.z*h4.z + w4.w*h4.w;
            }
        }
        __syncthreads();   // all h1 chunk reads done before h2 writes below

        // ---- phase B: serial recurrence (acc[tt] static -> stays in regs)
#pragma unroll
        for (int tt = 0; tt < CHUNK; ++tt) {
            const int rb = tt & 1;       // t0 multiple of 10 -> (t0+tt)&1==tt&1
            float a0 = acc[tt];
            float a1 = 0.f, a2 = 0.f, a3 = 0.f;
            float b0 = 0.f, b1 = 0.f, b2 = 0.f, b3 = 0.f;
#pragma unroll
            for (int k4 = 0; k4 < 16; k4 += 4) {
                float4 h0 = *(const float4*)(&h_s[rb][4*k4]);
                float4 h1 = *(const float4*)(&h_s[rb][4*k4 + 4]);
                float4 h2 = *(const float4*)(&h_s[rb][4*k4 + 8]);
                float4 h3 = *(const float4*)(&h_s[rb][4*k4 + 12]);
                a0 += w[4*k4   ]*h0.x + w[4*k4+ 1]*h0.y + w[4*k4+ 2]*h0.z + w[4*k4+ 3]*h0.w;
                a1 += w[4*k4+ 4]*h1.x + w[4*k4+ 5]*h1.y + w[4*k4+ 6]*h1.z + w[4*k4+ 7]*h1.w;
                a2 += w[4*k4+ 8]*h2.x + w[4*k4+ 9]*h2.y + w[4*k4+10]*h2.z + w[4*k4+11]*h2.w;
                a3 += w[4*k4+12]*h3.x + w[4*k4+13]*h3.y + w[4*k4+14]*h3.z + w[4*k4+15]*h3.w;
            }
            {
                const float* wlp = &Wl[tid * 64];
#pragma unroll
                for (int i = 0; i < 64; i += 16) {
                    float4 g0 = *(const float4*)(wlp + ((i     ) ^ rot));
                    float4 g1 = *(const float4*)(wlp + ((i +  4) ^ rot));
                    float4 g2 = *(const float4*)(wlp + ((i +  8) ^ rot));
                    float4 g3 = *(const float4*)(wlp + ((i + 12) ^ rot));
                    float4 h0 = *(const float4*)(&h_s[rb][64 + i]);
                    float4 h1 = *(const float4*)(&h_s[rb][64 + i + 4]);
                    float4 h2 = *(const float4*)(&h_s[rb][64 + i + 8]);
                    float4 h3 = *(const float4*)(&h_s[rb][64 + i + 12]);
                    b0 += g0.x*h0.x + g0.y*h0.y + g0.z*h0.z + g0.w*h0.w;
                    b1 += g1.x*h1.x + g1.y*h1.y + g1.z*h1.z + g1.w*h1.w;
                    b2 += g2.x*h2.x + g2.y*h2.y + g2.z*h2.z + g2.w*h2.w;
                    b3 += g3.x*h3.x + g3.y*h3.y + g3.z*h3.z + g3.w*h3.w;
                }
            }
            float acs = ((a0 + a1) + (a2 + a3)) + ((b0 + b1) + (b2 + b3));

            float av = (gt == 2) ? tanh_(acs) : sigmoid_(acs);
            float t1 = __shfl_xor(av, 1);
            float t2 = __shfl_xor(av, 2);
            float t3 = __shfl_xor(t1, 2);
            if (gt == 0) {
                c = t1 * c + av * t2;
                float h = t3 * tanh_(c);
                h_s[rb ^ 1][j] = h;
                hbB[(size_t)(t0 + tt) * HID + j] = h;   // h2 overwrites h1
            }
            __syncthreads();
        }
    }
}

// ---------------------------------------------------------------- FC head ---
__global__ void __launch_bounds__(256)
fc_head(const float* __restrict__ h_buf,  // h2 [64][3000][128]
        const float* __restrict__ fc1_w, const float* __restrict__ fc1_b,
        const float* __restrict__ fc2_w, const float* __restrict__ fc2_b,
        const float* __restrict__ fc3_w, const float* __restrict__ fc3_b,
        float* __restrict__ y_bt)         // [64][3000]
{
    __shared__ __align__(16) float w1[16 * HID];   // 8 KB
    __shared__ float sb[89];
    const int tid = threadIdx.x;
    for (int i = tid; i < 16 * HID; i += 256) w1[i] = fc1_w[i];
    if (tid < 16) sb[tid]      = fc1_b[tid];
    if (tid < 64) sb[16 + tid] = fc2_w[tid];
    if (tid < 4)  sb[80 + tid] = fc2_b[tid];
    if (tid < 4)  sb[84 + tid] = fc3_w[tid];
    if (tid == 0) sb[88]       = fc3_b[0];
    __syncthreads();

    const int idx = blockIdx.x * 256 + tid;        // b*3000 + t
    if (idx >= BATCH * T_STEPS) return;
    const float* h = h_buf + (size_t)idx * HID;

    float y1[16];
#pragma unroll
    for (int jo = 0; jo < 16; ++jo) y1[jo] = sb[jo];
#pragma unroll 4
    for (int k4 = 0; k4 < 32; ++k4) {
        float4 hv = *(const float4*)(h + 4 * k4);
#pragma unroll
        for (int jo = 0; jo < 16; ++jo) {
            float4 wv = *(const float4*)(&w1[jo * HID + 4 * k4]);
            y1[jo] += wv.x*hv.x + wv.y*hv.y + wv.z*hv.z + wv.w*hv.w;
        }
    }
    float y2[4];
#pragma unroll
    for (int jo = 0; jo < 4; ++jo) {
        float a = sb[80 + jo];
#pragma unroll
        for (int k = 0; k < 16; ++k) a += sb[16 + jo * 16 + k] * fmaxf(y1[k], 0.0f);
        y2[jo] = fmaxf(a, 0.0f);
    }
    float y = sb[88];
#pragma unroll
    for (int k = 0; k < 4; ++k) y += sb[84 + k] * y2[k];

    y_bt[idx] = y;   // coalesced (t fast)
}

// ------------------------------------------------------------- FD stencil ---
// phi row 0: (-1.5,2,-0.5)/dt ; rows 1..n-2: (-0.5,0,0.5)/dt ;
// row n-1: (0.5,-2,1.5)/dt.  Applied twice = exact phi@(phi@y).
__global__ void deriv_k(const float* __restrict__ in,   // [64][3000]
                        float* __restrict__ outp)       // [64][3000]
{
    const int idx = blockIdx.x * blockDim.x + threadIdx.x;
    if (idx >= BATCH * T_STEPS) return;
    const int t = idx % T_STEPS;
    float v;
    if (t == 0) {
        v = (-1.5f * in[idx] + 2.0f * in[idx + 1] - 0.5f * in[idx + 2]) * INV_DT;
    } else if (t == T_STEPS - 1) {
        v = (0.5f * in[idx - 2] - 2.0f * in[idx - 1] + 1.5f * in[idx]) * INV_DT;
    } else {
        v = (in[idx + 1] - in[idx - 1]) * (0.5f * INV_DT);
    }
    outp[idx] = v;
}

// ------------------------------------------------------------------ launch --
extern "C" void kernel_launch(void* const* d_in, const int* in_sizes, int n_in,
                              void* d_out, int out_size, void* d_ws, size_t ws_size,
                              hipStream_t stream)
{
    const float* x     = (const float*)d_in[0];
    const float* w_ih0 = (const float*)d_in[1];
    const float* w_hh0 = (const float*)d_in[2];
    const float* b_ih0 = (const float*)d_in[3];
    const float* b_hh0 = (const float*)d_in[4];
    const float* w_ih1 = (const float*)d_in[5];
    const float* w_hh1 = (const float*)d_in[6];
    const float* b_ih1 = (const float*)d_in[7];
    const float* b_hh1 = (const float*)d_in[8];
    const float* fc1_w = (const float*)d_in[9];
    const float* fc1_b = (const float*)d_in[10];
    const float* fc2_w = (const float*)d_in[11];
    const float* fc2_b = (const float*)d_in[12];
    const float* fc3_w = (const float*)d_in[13];
    const float* fc3_b = (const float*)d_in[14];
    float* out = (float*)d_out;

    // ws layout: h buffer (98.304 MB) | y (0.768 MB) | z (0.768 MB)
    float* h_buf = (float*)d_ws;
    float* y_bt  = (float*)((char*)d_ws + 98304000);
    float* z_bt  = (float*)((char*)d_ws + 98304000 + 768000);

    lstm_layer0<<<dim3(BATCH), dim3(512), 0, stream>>>(x, w_ih0, w_hh0, b_ih0, b_hh0, h_buf);
    lstm_layer1<<<dim3(BATCH), dim3(512), 0, stream>>>(w_ih1, w_hh1, b_ih1, b_hh1, h_buf);

    const int nelem = T_STEPS * BATCH;   // 192000 = 750 * 256
    fc_head<<<dim3(nelem / 256), dim3(256), 0, stream>>>(
        h_buf, fc1_w, fc1_b, fc2_w, fc2_b, fc3_w, fc3_b, y_bt);
    deriv_k<<<dim3(nelem / 256), dim3(256), 0, stream>>>(y_bt, z_bt);
    deriv_k<<<dim3(nelem / 256), dim3(256), 0, stream>>>(z_bt, out);
}

// Round 8
// 14082.446 us; speedup vs baseline: 4.9237x; 1.1141x over previous
//
#include <hip/hip_runtime.h>
#include <math.h>

// ---------------------------------------------------------------------------
// PhyRNN: 2-layer LSTM (B=64, T=3000, I=8, H=128) + FC head + double FD deriv.
//
// R8. History: R1 16.6 / R2 36.5 / R3 18.6 / R4 27.2 / R6 69.3 / R7 15.7 ms.
//  R7 proved: 512thr kernel, w[64] VGPR + 64 LDS -> VGPR=88/128, no spill,
//  weights resident. Remaining cost: (a) 32 uniform h-broadcast b128/step,
//  (b) Wl bank layout (9.8e7 conflicts), (c) layer1 phase A = 2x FMA inside
//  the serial kernel.
//  R8:
//   * xp_proj kernel precomputes layer1's input projection into ws (393 MB,
//     guarded by ws_size >= 494 MB; else fall back to R7-verbatim layer1).
//   * 4-lane team map: tid=j*4+q; lane q = K-quarter [32q,32q+32) of ALL 4
//     gates of unit j. h reads 8 b128/step (was 32). 4x4 shfl transpose
//     (3 shfls) puts gate q on lane q; then R1-proven 3-shfl combine.
//   * w[96] VGPR (gates i,f,g) + gate o in LDS (32 fl/thread, 64 KB/step).
//     R7 measured w[64]+temps = 88 VGPR -> w[96]+temps ~ 122 < 128 cap.
//   * Wl stored [i][tid] (wave-contiguous float4, conflict-free); h quarters
//     padded 40 floats apart -> 4 team addrs hit 4 distinct bank quads.
//
// Precision: fp32 (no fp32 MFMA on CDNA4; double FD deriv amplifies noise).
// ws: h 98.304 MB | y 0.768 | z 0.768 | xp 393.216 (if ws_size allows).
// ---------------------------------------------------------------------------

#define T_STEPS 3000
#define BATCH   64
#define HID     128
#define INV_DT  50.0f   // 1/0.02

__device__ __forceinline__ float sigmoid_(float x) {
    return 1.0f / (1.0f + __expf(-x));
}
__device__ __forceinline__ float tanh_(float x) {
    return 1.0f - 2.0f / (__expf(2.0f * x) + 1.0f);
}

// ---------------------------------------------------------------- layer 0 ---
// 64 blocks, 512 thr. tid = j*4 + q. Lane q: K-quarter q of gates i,f,g
// (VGPR w[96]) and gate o (LDS). After transpose lane q holds gate q.
__global__ void __launch_bounds__(512)
lstm_layer0(const float* __restrict__ x,      // [64][3000][8]
            const float* __restrict__ w_ih,   // [512][8]
            const float* __restrict__ w_hh,   // [512][128]
            const float* __restrict__ b_ih,
            const float* __restrict__ b_hh,
            float* __restrict__ h_out)        // [64][3000][128]
{
    const int b   = blockIdx.x;
    const int tid = threadIdx.x;
    const int j   = tid >> 2;            // hidden unit
    const int q   = tid & 3;             // K-quarter AND final gate id
    const int kq  = q * 32;

    __shared__ __align__(16) float4 Wl4[8 * 512];    // gate-o weights, 64 KB
    __shared__ __align__(16) float  h_pad[2][160];   // 4 quarters, 40 apart

    // gates i,f,g K-quarter -> VGPRs (96 floats)
    float w[96];
#pragma unroll
    for (int g = 0; g < 3; ++g) {
#pragma unroll
        for (int i = 0; i < 32; i += 4) {
            float4 v = *(const float4*)(w_hh + (size_t)(g * HID + j) * HID + kq + i);
            w[g*32 + i] = v.x; w[g*32 + i+1] = v.y; w[g*32 + i+2] = v.z; w[g*32 + i+3] = v.w;
        }
    }
    // gate o K-quarter -> LDS, [i][tid] wave-contiguous layout
#pragma unroll
    for (int i = 0; i < 8; ++i)
        Wl4[i * 512 + tid] = *(const float4*)(w_hh + (size_t)(3 * HID + j) * HID + kq + 4 * i);

    float wi[8];                         // W_ih row for gate q of unit j
#pragma unroll
    for (int i = 0; i < 8; i += 4) {
        float4 v = *(const float4*)(w_ih + (size_t)(q * HID + j) * 8 + i);
        wi[i] = v.x; wi[i+1] = v.y; wi[i+2] = v.z; wi[i+3] = v.w;
    }
    const float bias = b_ih[q * HID + j] + b_hh[q * HID + j];
    float c = 0.0f;                      // valid on q==0 lanes

    if (tid < 160) h_pad[0][tid] = 0.0f;
    __syncthreads();

    const float* xrow = x + (size_t)b * T_STEPS * 8;
    float* hb = h_out + (size_t)b * T_STEPS * HID;

#pragma unroll 1
    for (int t = 0; t < T_STEPS; ++t) {
        const int rb = t & 1;
        float4 xa = *(const float4*)(xrow + t * 8);
        float4 xc = *(const float4*)(xrow + t * 8 + 4);
        float xterm = bias
                    + wi[0]*xa.x + wi[1]*xa.y + wi[2]*xa.z + wi[3]*xa.w
                    + wi[4]*xc.x + wi[5]*xc.y + wi[6]*xc.z + wi[7]*xc.w;

        float a0 = 0.f, a1 = 0.f, a2 = 0.f, a3 = 0.f;   // i,f,g,o partials
        const float* hq = &h_pad[rb][40 * q];
#pragma unroll
        for (int i = 0; i < 8; ++i) {
            float4 hv = *(const float4*)(hq + 4 * i);
            float4 g4 = Wl4[i * 512 + tid];
            a0 += w[     4*i]*hv.x + w[     4*i+1]*hv.y + w[     4*i+2]*hv.z + w[     4*i+3]*hv.w;
            a1 += w[32 + 4*i]*hv.x + w[32 + 4*i+1]*hv.y + w[32 + 4*i+2]*hv.z + w[32 + 4*i+3]*hv.w;
            a2 += w[64 + 4*i]*hv.x + w[64 + 4*i+1]*hv.y + w[64 + 4*i+2]*hv.z + w[64 + 4*i+3]*hv.w;
            a3 += g4.x*hv.x + g4.y*hv.y + g4.z*hv.z + g4.w*hv.w;
        }
        // 4x4 transpose-reduce: lane q ends with full pre-activation of gate q
        float s0 = __shfl_xor((q & 1) ? a0 : a1, 1);
        float s1 = __shfl_xor((q & 1) ? a2 : a3, 1);
        float p0 = ((q & 1) ? a1 : a0) + s0;
        float p1 = ((q & 1) ? a3 : a2) + s1;
        float S  = ((q & 2) ? p1 : p0) + __shfl_xor((q & 2) ? p0 : p1, 2);
        S += xterm;

        float av = (q == 2) ? tanh_(S) : sigmoid_(S);
        float t1 = __shfl_xor(av, 1);
        float t2 = __shfl_xor(av, 2);
        float t3 = __shfl_xor(t1, 2);
        if (q == 0) {                    // av=sig_i t1=sig_f t2=tanh_g t3=sig_o
            c = t1 * c + av * t2;
            float h = t3 * tanh_(c);
            h_pad[rb ^ 1][(j & 31) + 40 * (j >> 5)] = h;
            hb[(size_t)t * HID + j] = h;
        }
        __syncthreads();
    }
}

// ----------------------------------------------------- xp projection pass ---
// xp[b][t][r] = b_ih1[r]+b_hh1[r] + W_ih1[r] . h1[b][t]. Parallel GEMV batch.
// Grid 64*125; block handles (b, 24 t's); thread r streams its W row k-outer.
__global__ void __launch_bounds__(512)
xp_proj(const float* __restrict__ w_ih,   // [512][128]
        const float* __restrict__ b_ih,
        const float* __restrict__ b_hh,
        const float* __restrict__ h1,     // [64][3000][128]
        float* __restrict__ xp)           // [64][3000][512]
{
    const int blk = blockIdx.x;
    const int b   = blk / 125;
    const int t0  = (blk % 125) * 24;
    const int r   = threadIdx.x;

    float acc[24];
    const float bias = b_ih[r] + b_hh[r];
#pragma unroll
    for (int u = 0; u < 24; ++u) acc[u] = bias;

    const float* hp = h1 + ((size_t)b * T_STEPS + t0) * HID;
    const float* wr = w_ih + (size_t)r * HID;
#pragma unroll 2
    for (int k4 = 0; k4 < 32; ++k4) {
        float4 w4 = *(const float4*)(wr + 4 * k4);
#pragma unroll
        for (int u = 0; u < 24; ++u) {
            float4 h4 = *(const float4*)(hp + u * HID + 4 * k4);   // uniform
            acc[u] += w4.x*h4.x + w4.y*h4.y + w4.z*h4.z + w4.w*h4.w;
        }
    }
    float* xo = xp + ((size_t)b * T_STEPS + t0) * 512 + r;
#pragma unroll
    for (int u = 0; u < 24; ++u) xo[(size_t)u * 512] = acc[u];   // coalesced
}

// ------------------------------------------- layer 1 (xp precomputed path) --
__global__ void __launch_bounds__(512)
lstm_layer1_pre(const float* __restrict__ w_hh,   // [512][128]
                const float* __restrict__ xp,     // [64][3000][512]
                float* __restrict__ h_buf)        // in: h1, out: h2 (in place)
{
    const int b   = blockIdx.x;
    const int tid = threadIdx.x;
    const int j   = tid >> 2;
    const int q   = tid & 3;
    const int kq  = q * 32;

    __shared__ __align__(16) float4 Wl4[8 * 512];
    __shared__ __align__(16) float  h_pad[2][160];

    float w[96];
#pragma unroll
    for (int g = 0; g < 3; ++g) {
#pragma unroll
        for (int i = 0; i < 32; i += 4) {
            float4 v = *(const float4*)(w_hh + (size_t)(g * HID + j) * HID + kq + i);
            w[g*32 + i] = v.x; w[g*32 + i+1] = v.y; w[g*32 + i+2] = v.z; w[g*32 + i+3] = v.w;
        }
    }
#pragma unroll
    for (int i = 0; i < 8; ++i)
        Wl4[i * 512 + tid] = *(const float4*)(w_hh + (size_t)(3 * HID + j) * HID + kq + 4 * i);

    float c = 0.0f;
    if (tid < 160) h_pad[0][tid] = 0.0f;
    __syncthreads();

    float* hb = h_buf + (size_t)b * T_STEPS * HID;
    const float* xpb = xp + (size_t)b * T_STEPS * 512 + q * HID + j;

    float xq = xpb[0];                   // prefetch depth 1 (bias included)
#pragma unroll 1
    for (int t = 0; t < T_STEPS; ++t) {
        const int rb = t & 1;
        const int tn = (t + 1 < T_STEPS) ? t + 1 : t;
        float xq_n = xpb[(size_t)tn * 512];

        float a0 = 0.f, a1 = 0.f, a2 = 0.f, a3 = 0.f;
        const float* hq = &h_pad[rb][40 * q];
#pragma unroll
        for (int i = 0; i < 8; ++i) {
            float4 hv = *(const float4*)(hq + 4 * i);
            float4 g4 = Wl4[i * 512 + tid];
            a0 += w[     4*i]*hv.x + w[     4*i+1]*hv.y + w[     4*i+2]*hv.z + w[     4*i+3]*hv.w;
            a1 += w[32 + 4*i]*hv.x + w[32 + 4*i+1]*hv.y + w[32 + 4*i+2]*hv.z + w[32 + 4*i+3]*hv.w;
            a2 += w[64 + 4*i]*hv.x + w[64 + 4*i+1]*hv.y + w[64 + 4*i+2]*hv.z + w[64 + 4*i+3]*hv.w;
            a3 += g4.x*hv.x + g4.y*hv.y + g4.z*hv.z + g4.w*hv.w;
        }
        float s0 = __shfl_xor((q & 1) ? a0 : a1, 1);
        float s1 = __shfl_xor((q & 1) ? a2 : a3, 1);
        float p0 = ((q & 1) ? a1 : a0) + s0;
        float p1 = ((q & 1) ? a3 : a2) + s1;
        float S  = ((q & 2) ? p1 : p0) + __shfl_xor((q & 2) ? p0 : p1, 2);
        S += xq;

        float av = (q == 2) ? tanh_(S) : sigmoid_(S);
        float t1 = __shfl_xor(av, 1);
        float t2 = __shfl_xor(av, 2);
        float t3 = __shfl_xor(t1, 2);
        if (q == 0) {
            c = t1 * c + av * t2;
            float h = t3 * tanh_(c);
            h_pad[rb ^ 1][(j & 31) + 40 * (j >> 5)] = h;
            hb[(size_t)t * HID + j] = h;     // h2 overwrites h1
        }
        xq = xq_n;
        __syncthreads();
    }
}

// --------------------------- layer 1 fallback (R7 verbatim, ws too small) ---
#define CHUNK   10
__global__ void __launch_bounds__(512)
lstm_layer1_fused(const float* __restrict__ w_ih,
                  const float* __restrict__ w_hh,
                  const float* __restrict__ b_ih,
                  const float* __restrict__ b_hh,
                  float* __restrict__ h_buf)
{
    const int b   = blockIdx.x;
    const int tid = threadIdx.x;
    const int j   = tid >> 2;
    const int gt  = tid & 3;
    const int r   = gt * HID + j;
    const int rot = (tid & 7) << 2;

    __shared__ __align__(16) float Wl[512 * 64];
    __shared__ __align__(16) float h_s[2][HID];

    float w[64];
#pragma unroll
    for (int i = 0; i < 64; i += 4) {
        float4 v = *(const float4*)(w_hh + (size_t)r * HID + i);
        w[i] = v.x; w[i+1] = v.y; w[i+2] = v.z; w[i+3] = v.w;
    }
#pragma unroll
    for (int i = 0; i < 64; i += 4) {
        float4 v = *(const float4*)(w_hh + (size_t)r * HID + 64 + i);
        *(float4*)&Wl[tid * 64 + (i ^ rot)] = v;
    }
    const float bias = b_ih[r] + b_hh[r];
    float c = 0.0f;
    if (tid < HID) h_s[0][tid] = 0.0f;
    __syncthreads();

    float* hbB = h_buf + (size_t)b * T_STEPS * HID;
    const float* wihr = w_ih + (size_t)r * HID;

    for (int t0 = 0; t0 < T_STEPS; t0 += CHUNK) {
        float acc[CHUNK];
#pragma unroll
        for (int tau = 0; tau < CHUNK; ++tau) acc[tau] = bias;
        const float* hp = hbB + (size_t)t0 * HID;
#pragma unroll 2
        for (int k4 = 0; k4 < 32; ++k4) {
            float4 w4 = *(const float4*)(wihr + 4 * k4);
#pragma unroll
            for (int tau = 0; tau < CHUNK; ++tau) {
                float4 h4 = *(const float4*)(hp + tau * HID + 4 * k4);
                acc[tau] += w4.x*h4.x + w4.y*h4.y + w4.z*h4.z + w4.w*h4.w;
            }
        }
        __syncthreads();

#pragma unroll
        for (int tt = 0; tt < CHUNK; ++tt) {
            const int rb = tt & 1;
            float a0 = acc[tt];
            float a1 = 0.f, a2 = 0.f, a3 = 0.f;
            float b0 = 0.f, b1 = 0.f, b2 = 0.f, b3 = 0.f;
#pragma unroll
            for (int k4 = 0; k4 < 16; k4 += 4) {
                float4 h0 = *(const float4*)(&h_s[rb][4*k4]);
                float4 h1 = *(const float4*)(&h_s[rb][4*k4 + 4]);
                float4 h2 = *(const float4*)(&h_s[rb][4*k4 + 8]);
                float4 h3 = *(const float4*)(&h_s[rb][4*k4 + 12]);
                a0 += w[4*k4   ]*h0.x + w[4*k4+ 1]*h0.y + w[4*k4+ 2]*h0.z + w[4*k4+ 3]*h0.w;
                a1 += w[4*k4+ 4]*h1.x + w[4*k4+ 5]*h1.y + w[4*k4+ 6]*h1.z + w[4*k4+ 7]*h1.w;
                a2 += w[4*k4+ 8]*h2.x + w[4*k4+ 9]*h2.y + w[4*k4+10]*h2.z + w[4*k4+11]*h2.w;
                a3 += w[4*k4+12]*h3.x + w[4*k4+13]*h3.y + w[4*k4+14]*h3.z + w[4*k4+15]*h3.w;
            }
            {
                const float* wlp = &Wl[tid * 64];
#pragma unroll
                for (int i = 0; i < 64; i += 16) {
                    float4 g0 = *(const float4*)(wlp + ((i     ) ^ rot));
                    float4 g1 = *(const float4*)(wlp + ((i +  4) ^ rot));
                    float4 g2 = *(const float4*)(wlp + ((i +  8) ^ rot));
                    float4 g3 = *(const float4*)(wlp + ((i + 12) ^ rot));
                    float4 h0 = *(const float4*)(&h_s[rb][64 + i]);
                    float4 h1 = *(const float4*)(&h_s[rb][64 + i + 4]);
                    float4 h2 = *(const float4*)(&h_s[rb][64 + i + 8]);
                    float4 h3 = *(const float4*)(&h_s[rb][64 + i + 12]);
                    b0 += g0.x*h0.x + g0.y*h0.y + g0.z*h0.z + g0.w*h0.w;
                    b1 += g1.x*h1.x + g1.y*h1.y + g1.z*h1.z + g1.w*h1.w;
                    b2 += g2.x*h2.x + g2.y*h2.y + g2.z*h2.z + g2.w*h2.w;
                    b3 += g3.x*h3.x + g3.y*h3.y + g3.z*h3.z + g3.w*h3.w;
                }
            }
            float acs = ((a0 + a1) + (a2 + a3)) + ((b0 + b1) + (b2 + b3));

            float av = (gt == 2) ? tanh_(acs) : sigmoid_(acs);
            float t1 = __shfl_xor(av, 1);
            float t2 = __shfl_xor(av, 2);
            float t3 = __shfl_xor(t1, 2);
            if (gt == 0) {
                c = t1 * c + av * t2;
                float h = t3 * tanh_(c);
                h_s[rb ^ 1][j] = h;
                hbB[(size_t)(t0 + tt) * HID + j] = h;
            }
            __syncthreads();
        }
    }
}

// ---------------------------------------------------------------- FC head ---
__global__ void __launch_bounds__(256)
fc_head(const float* __restrict__ h_buf,
        const float* __restrict__ fc1_w, const float* __restrict__ fc1_b,
        const float* __restrict__ fc2_w, const float* __restrict__ fc2_b,
        const float* __restrict__ fc3_w, const float* __restrict__ fc3_b,
        float* __restrict__ y_bt)         // [64][3000]
{
    __shared__ __align__(16) float w1[16 * HID];
    __shared__ float sb[89];
    const int tid = threadIdx.x;
    for (int i = tid; i < 16 * HID; i += 256) w1[i] = fc1_w[i];
    if (tid < 16) sb[tid]      = fc1_b[tid];
    if (tid < 64) sb[16 + tid] = fc2_w[tid];
    if (tid < 4)  sb[80 + tid] = fc2_b[tid];
    if (tid < 4)  sb[84 + tid] = fc3_w[tid];
    if (tid == 0) sb[88]       = fc3_b[0];
    __syncthreads();

    const int idx = blockIdx.x * 256 + tid;        // b*3000 + t
    if (idx >= BATCH * T_STEPS) return;
    const float* h = h_buf + (size_t)idx * HID;

    float y1[16];
#pragma unroll
    for (int jo = 0; jo < 16; ++jo) y1[jo] = sb[jo];
#pragma unroll 4
    for (int k4 = 0; k4 < 32; ++k4) {
        float4 hv = *(const float4*)(h + 4 * k4);
#pragma unroll
        for (int jo = 0; jo < 16; ++jo) {
            float4 wv = *(const float4*)(&w1[jo * HID + 4 * k4]);
            y1[jo] += wv.x*hv.x + wv.y*hv.y + wv.z*hv.z + wv.w*hv.w;
        }
    }
    float y2[4];
#pragma unroll
    for (int jo = 0; jo < 4; ++jo) {
        float a = sb[80 + jo];
#pragma unroll
        for (int k = 0; k < 16; ++k) a += sb[16 + jo * 16 + k] * fmaxf(y1[k], 0.0f);
        y2[jo] = fmaxf(a, 0.0f);
    }
    float y = sb[88];
#pragma unroll
    for (int k = 0; k < 4; ++k) y += sb[84 + k] * y2[k];

    y_bt[idx] = y;
}

// ------------------------------------------------------------- FD stencil ---
__global__ void deriv_k(const float* __restrict__ in,   // [64][3000]
                        float* __restrict__ outp)       // [64][3000]
{
    const int idx = blockIdx.x * blockDim.x + threadIdx.x;
    if (idx >= BATCH * T_STEPS) return;
    const int t = idx % T_STEPS;
    float v;
    if (t == 0) {
        v = (-1.5f * in[idx] + 2.0f * in[idx + 1] - 0.5f * in[idx + 2]) * INV_DT;
    } else if (t == T_STEPS - 1) {
        v = (0.5f * in[idx - 2] - 2.0f * in[idx - 1] + 1.5f * in[idx]) * INV_DT;
    } else {
        v = (in[idx + 1] - in[idx - 1]) * (0.5f * INV_DT);
    }
    outp[idx] = v;
}

// ------------------------------------------------------------------ launch --
extern "C" void kernel_launch(void* const* d_in, const int* in_sizes, int n_in,
                              void* d_out, int out_size, void* d_ws, size_t ws_size,
                              hipStream_t stream)
{
    const float* x     = (const float*)d_in[0];
    const float* w_ih0 = (const float*)d_in[1];
    const float* w_hh0 = (const float*)d_in[2];
    const float* b_ih0 = (const float*)d_in[3];
    const float* b_hh0 = (const float*)d_in[4];
    const float* w_ih1 = (const float*)d_in[5];
    const float* w_hh1 = (const float*)d_in[6];
    const float* b_ih1 = (const float*)d_in[7];
    const float* b_hh1 = (const float*)d_in[8];
    const float* fc1_w = (const float*)d_in[9];
    const float* fc1_b = (const float*)d_in[10];
    const float* fc2_w = (const float*)d_in[11];
    const float* fc2_b = (const float*)d_in[12];
    const float* fc3_w = (const float*)d_in[13];
    const float* fc3_b = (const float*)d_in[14];
    float* out = (float*)d_out;

    // ws: h 98,304,000 | y 768,000 | z 768,000 | xp 393,216,000
    float* h_buf = (float*)d_ws;
    float* y_bt  = (float*)((char*)d_ws + 98304000);
    float* z_bt  = (float*)((char*)d_ws + 98304000 + 768000);
    float* xp    = (float*)((char*)d_ws + 98304000 + 1536000);
    const bool use_pre = ws_size >= (size_t)98304000 + 1536000 + 393216000;

    lstm_layer0<<<dim3(BATCH), dim3(512), 0, stream>>>(x, w_ih0, w_hh0, b_ih0, b_hh0, h_buf);

    if (use_pre) {
        xp_proj<<<dim3(BATCH * 125), dim3(512), 0, stream>>>(w_ih1, b_ih1, b_hh1, h_buf, xp);
        lstm_layer1_pre<<<dim3(BATCH), dim3(512), 0, stream>>>(w_hh1, xp, h_buf);
    } else {
        lstm_layer1_fused<<<dim3(BATCH), dim3(512), 0, stream>>>(w_ih1, w_hh1, b_ih1, b_hh1, h_buf);
    }

    const int nelem = T_STEPS * BATCH;   // 192000 = 750 * 256
    fc_head<<<dim3(nelem / 256), dim3(256), 0, stream>>>(
        h_buf, fc1_w, fc1_b, fc2_w, fc2_b, fc3_w, fc3_b, y_bt);
    deriv_k<<<dim3(nelem / 256), dim3(256), 0, stream>>>(y_bt, z_bt);
    deriv_k<<<dim3(nelem / 256), dim3(256), 0, stream>>>(z_bt, out);
}

// Round 10
// 13680.121 us; speedup vs baseline: 5.0685x; 1.0294x over previous
//
#include <hip/hip_runtime.h>
#include <math.h>

// ---------------------------------------------------------------------------
// PhyRNN: 2-layer LSTM (B=64, T=3000, I=8, H=128) + FC head + double FD deriv.
//
// R10 = R9 resubmitted (R9 hit GPUAcquisitionTimeout before running; design
// untested, not falsified).
// History: R1 16.6 / R2 36.5 / R3 18.6 / R4 27.2 / R6 69.3 / R7 15.7 /
//          R8 14.1 ms.
//  R8 learned: (a) ws_size < 494 MB -> xp precompute path never ran;
//  (b) team-map layer0 = 2.5 ms, zero conflicts, but VGPR=80 < w[96] demand
//      -> partial remat from L1/L2 (at 67 KB LDS the allocator minimizes).
//  ALLOCATOR (refined): at 132 KB LDS / 1 blk/CU it grants 128 and keeps
//  demand<=~110 resident (R7 layer1 proof). At lower LDS it minimizes.
//  R9/R10: BOTH kernels: team map (tid=j*4+q, lane q owns K-quarter
//      [32q,32q+32) of all 4 gates of unit j) + w[64] VGPR (W_hh gates i,f
//      quarters) + W_hh gates g,o quarters in LDS ([i][tid] float4 layout,
//      conflict-free, 2x64 KB) -> LDS 129.3 KB -> 1 blk/CU -> proven-resident
//      regime. h quarters in padded LDS 40 floats apart (4 bank quads).
//      Layer1 = fused: R7-proven phase A (W_ih full row r=q*128+j streamed
//      k-outer from L2 into acc[8] regs; lane already matches phase-B gate)
//      + team-map phase B adding acc[tt].
//
// Per-step pipeline (phase B): 8x { h b128 (broadcast x4 addrs) ; 2x Wl b128 ;
// 16 FMA } ; 4x4 shfl transpose-reduce (3 shfl) ; act ; 3-shfl gate combine ;
// q==0 lane updates c,h. One barrier/step.
//
// Precision: fp32 (no fp32 MFMA on CDNA4; double FD deriv amplifies noise).
// ws: h 98.304 MB | y 0.768 | z 0.768 (proven fit).
// ---------------------------------------------------------------------------

#define T_STEPS 3000
#define BATCH   64
#define HID     128
#define CHUNK   8       // 3000 = 375*8
#define INV_DT  50.0f   // 1/0.02

__device__ __forceinline__ float sigmoid_(float x) {
    return 1.0f / (1.0f + __expf(-x));
}
__device__ __forceinline__ float tanh_(float x) {
    return 1.0f - 2.0f / (__expf(2.0f * x) + 1.0f);
}

// ---------------------------------------------------------------- layer 0 ---
__global__ void __launch_bounds__(512)
lstm_layer0(const float* __restrict__ x,      // [64][3000][8]
            const float* __restrict__ w_ih,   // [512][8]
            const float* __restrict__ w_hh,   // [512][128]
            const float* __restrict__ b_ih,
            const float* __restrict__ b_hh,
            float* __restrict__ h_out)        // [64][3000][128]
{
    const int b   = blockIdx.x;
    const int tid = threadIdx.x;
    const int j   = tid >> 2;            // hidden unit
    const int q   = tid & 3;             // K-quarter AND final gate id
    const int kq  = q * 32;

    __shared__ __align__(16) float4 WlG[8 * 512];    // gate-g W_hh, 64 KB
    __shared__ __align__(16) float4 WlO[8 * 512];    // gate-o W_hh, 64 KB
    __shared__ __align__(16) float  h_pad[2][160];   // quarters 40 apart

    // gates i,f K-quarter -> VGPRs (64 floats)
    float w[64];
#pragma unroll
    for (int g = 0; g < 2; ++g) {
#pragma unroll
        for (int i = 0; i < 32; i += 4) {
            float4 v = *(const float4*)(w_hh + (size_t)(g * HID + j) * HID + kq + i);
            w[g*32 + i] = v.x; w[g*32 + i+1] = v.y; w[g*32 + i+2] = v.z; w[g*32 + i+3] = v.w;
        }
    }
    // gates g,o K-quarter -> LDS, [i][tid] wave-contiguous layout
#pragma unroll
    for (int i = 0; i < 8; ++i) {
        WlG[i * 512 + tid] = *(const float4*)(w_hh + (size_t)(2 * HID + j) * HID + kq + 4 * i);
        WlO[i * 512 + tid] = *(const float4*)(w_hh + (size_t)(3 * HID + j) * HID + kq + 4 * i);
    }
    float wi[8];                         // W_ih row for gate q of unit j
#pragma unroll
    for (int i = 0; i < 8; i += 4) {
        float4 v = *(const float4*)(w_ih + (size_t)(q * HID + j) * 8 + i);
        wi[i] = v.x; wi[i+1] = v.y; wi[i+2] = v.z; wi[i+3] = v.w;
    }
    const float bias = b_ih[q * HID + j] + b_hh[q * HID + j];
    float c = 0.0f;                      // valid on q==0 lanes

    if (tid < 160) h_pad[0][tid] = 0.0f;
    __syncthreads();

    const float* xrow = x + (size_t)b * T_STEPS * 8;
    float* hb = h_out + (size_t)b * T_STEPS * HID;

#pragma unroll 1
    for (int t = 0; t < T_STEPS; ++t) {
        const int rb = t & 1;
        float4 xa = *(const float4*)(xrow + t * 8);
        float4 xc = *(const float4*)(xrow + t * 8 + 4);
        float xterm = bias
                    + wi[0]*xa.x + wi[1]*xa.y + wi[2]*xa.z + wi[3]*xa.w
                    + wi[4]*xc.x + wi[5]*xc.y + wi[6]*xc.z + wi[7]*xc.w;

        float a0 = 0.f, a1 = 0.f, a2 = 0.f, a3 = 0.f;   // i,f,g,o partials
        const float* hq = &h_pad[rb][40 * q];
#pragma unroll
        for (int i = 0; i < 8; ++i) {
            float4 hv = *(const float4*)(hq + 4 * i);
            float4 g2 = WlG[i * 512 + tid];
            float4 g3 = WlO[i * 512 + tid];
            a0 += w[     4*i]*hv.x + w[     4*i+1]*hv.y + w[     4*i+2]*hv.z + w[     4*i+3]*hv.w;
            a1 += w[32 + 4*i]*hv.x + w[32 + 4*i+1]*hv.y + w[32 + 4*i+2]*hv.z + w[32 + 4*i+3]*hv.w;
            a2 += g2.x*hv.x + g2.y*hv.y + g2.z*hv.z + g2.w*hv.w;
            a3 += g3.x*hv.x + g3.y*hv.y + g3.z*hv.z + g3.w*hv.w;
        }
        // 4x4 transpose-reduce (R8-proven): lane q gets full sum of gate q
        float s0 = __shfl_xor((q & 1) ? a0 : a1, 1);
        float s1 = __shfl_xor((q & 1) ? a2 : a3, 1);
        float p0 = ((q & 1) ? a1 : a0) + s0;
        float p1 = ((q & 1) ? a3 : a2) + s1;
        float S  = ((q & 2) ? p1 : p0) + __shfl_xor((q & 2) ? p0 : p1, 2);
        S += xterm;

        float av = (q == 2) ? tanh_(S) : sigmoid_(S);
        float t1 = __shfl_xor(av, 1);
        float t2 = __shfl_xor(av, 2);
        float t3 = __shfl_xor(t1, 2);
        if (q == 0) {                    // av=sig_i t1=sig_f t2=tanh_g t3=sig_o
            c = t1 * c + av * t2;
            float h = t3 * tanh_(c);
            h_pad[rb ^ 1][(j & 31) + 40 * (j >> 5)] = h;
            hb[(size_t)t * HID + j] = h;
        }
        __syncthreads();
    }
}

// ------------------------------------------------------- layer 1 (fused) ---
// Phase A (R7-proven): acc[tau] = bias + W_ih[q*128+j] . h1[t0+tau] (K=128),
// W_ih streamed k-outer from L2, h1 wave-uniform loads. Lane q holds gate q's
// xp -- exactly what phase B's transpose-reduce output needs. Phase B: team-
// map recurrence adding acc[tt]. h2 overwrites h1 (barrier between phases).
__global__ void __launch_bounds__(512)
lstm_layer1(const float* __restrict__ w_ih,   // [512][128]
            const float* __restrict__ w_hh,   // [512][128]
            const float* __restrict__ b_ih,
            const float* __restrict__ b_hh,
            float* __restrict__ h_buf)        // in: h1, out: h2 (in place)
{
    const int b   = blockIdx.x;
    const int tid = threadIdx.x;
    const int j   = tid >> 2;
    const int q   = tid & 3;
    const int kq  = q * 32;

    __shared__ __align__(16) float4 WlG[8 * 512];    // 64 KB
    __shared__ __align__(16) float4 WlO[8 * 512];    // 64 KB
    __shared__ __align__(16) float  h_pad[2][160];

    float w[64];
#pragma unroll
    for (int g = 0; g < 2; ++g) {
#pragma unroll
        for (int i = 0; i < 32; i += 4) {
            float4 v = *(const float4*)(w_hh + (size_t)(g * HID + j) * HID + kq + i);
            w[g*32 + i] = v.x; w[g*32 + i+1] = v.y; w[g*32 + i+2] = v.z; w[g*32 + i+3] = v.w;
        }
    }
#pragma unroll
    for (int i = 0; i < 8; ++i) {
        WlG[i * 512 + tid] = *(const float4*)(w_hh + (size_t)(2 * HID + j) * HID + kq + 4 * i);
        WlO[i * 512 + tid] = *(const float4*)(w_hh + (size_t)(3 * HID + j) * HID + kq + 4 * i);
    }
    const float bias = b_ih[q * HID + j] + b_hh[q * HID + j];
    float c = 0.0f;
    if (tid < 160) h_pad[0][tid] = 0.0f;
    __syncthreads();

    float* hbB = h_buf + (size_t)b * T_STEPS * HID;
    const float* wihr = w_ih + (size_t)(q * HID + j) * HID;   // own full row

#pragma unroll 1
    for (int t0 = 0; t0 < T_STEPS; t0 += CHUNK) {
        // ---- phase A: acc[tau] = bias + W_ih[r] . h1[t0+tau]  (K=128)
        float acc[CHUNK];
#pragma unroll
        for (int tau = 0; tau < CHUNK; ++tau) acc[tau] = bias;
        const float* hp = hbB + (size_t)t0 * HID;
#pragma unroll 2
        for (int k4 = 0; k4 < 32; ++k4) {
            float4 w4 = *(const float4*)(wihr + 4 * k4);       // per-lane row
#pragma unroll
            for (int tau = 0; tau < CHUNK; ++tau) {
                float4 h4 = *(const float4*)(hp + tau * HID + 4 * k4); // uniform
                acc[tau] += w4.x*h4.x + w4.y*h4.y + w4.z*h4.z + w4.w*h4.w;
            }
        }
        __syncthreads();   // all h1 chunk reads complete before h2 writes

        // ---- phase B: serial recurrence (acc[tt] static)
#pragma unroll
        for (int tt = 0; tt < CHUNK; ++tt) {
            const int rb = tt & 1;       // t0 multiple of 8 -> (t0+tt)&1==tt&1
            float a0 = 0.f, a1 = 0.f, a2 = 0.f, a3 = 0.f;
            const float* hq = &h_pad[rb][40 * q];
#pragma unroll
            for (int i = 0; i < 8; ++i) {
                float4 hv = *(const float4*)(hq + 4 * i);
                float4 g2 = WlG[i * 512 + tid];
                float4 g3 = WlO[i * 512 + tid];
                a0 += w[     4*i]*hv.x + w[     4*i+1]*hv.y + w[     4*i+2]*hv.z + w[     4*i+3]*hv.w;
                a1 += w[32 + 4*i]*hv.x + w[32 + 4*i+1]*hv.y + w[32 + 4*i+2]*hv.z + w[32 + 4*i+3]*hv.w;
                a2 += g2.x*hv.x + g2.y*hv.y + g2.z*hv.z + g2.w*hv.w;
                a3 += g3.x*hv.x + g3.y*hv.y + g3.z*hv.z + g3.w*hv.w;
            }
            float s0 = __shfl_xor((q & 1) ? a0 : a1, 1);
            float s1 = __shfl_xor((q & 1) ? a2 : a3, 1);
            float p0 = ((q & 1) ? a1 : a0) + s0;
            float p1 = ((q & 1) ? a3 : a2) + s1;
            float S  = ((q & 2) ? p1 : p0) + __shfl_xor((q & 2) ? p0 : p1, 2);
            S += acc[tt];

            float av = (q == 2) ? tanh_(S) : sigmoid_(S);
            float t1 = __shfl_xor(av, 1);
            float t2 = __shfl_xor(av, 2);
            float t3 = __shfl_xor(t1, 2);
            if (q == 0) {
                c = t1 * c + av * t2;
                float h = t3 * tanh_(c);
                h_pad[rb ^ 1][(j & 31) + 40 * (j >> 5)] = h;
                hbB[(size_t)(t0 + tt) * HID + j] = h;   // h2 overwrites h1
            }
            __syncthreads();
        }
    }
}

// ---------------------------------------------------------------- FC head ---
__global__ void __launch_bounds__(256)
fc_head(const float* __restrict__ h_buf,
        const float* __restrict__ fc1_w, const float* __restrict__ fc1_b,
        const float* __restrict__ fc2_w, const float* __restrict__ fc2_b,
        const float* __restrict__ fc3_w, const float* __restrict__ fc3_b,
        float* __restrict__ y_bt)         // [64][3000]
{
    __shared__ __align__(16) float w1[16 * HID];
    __shared__ float sb[89];
    const int tid = threadIdx.x;
    for (int i = tid; i < 16 * HID; i += 256) w1[i] = fc1_w[i];
    if (tid < 16) sb[tid]      = fc1_b[tid];
    if (tid < 64) sb[16 + tid] = fc2_w[tid];
    if (tid < 4)  sb[80 + tid] = fc2_b[tid];
    if (tid < 4)  sb[84 + tid] = fc3_w[tid];
    if (tid == 0) sb[88]       = fc3_b[0];
    __syncthreads();

    const int idx = blockIdx.x * 256 + tid;        // b*3000 + t
    if (idx >= BATCH * T_STEPS) return;
    const float* h = h_buf + (size_t)idx * HID;

    float y1[16];
#pragma unroll
    for (int jo = 0; jo < 16; ++jo) y1[jo] = sb[jo];
#pragma unroll 4
    for (int k4 = 0; k4 < 32; ++k4) {
        float4 hv = *(const float4*)(h + 4 * k4);
#pragma unroll
        for (int jo = 0; jo < 16; ++jo) {
            float4 wv = *(const float4*)(&w1[jo * HID + 4 * k4]);
            y1[jo] += wv.x*hv.x + wv.y*hv.y + wv.z*hv.z + wv.w*hv.w;
        }
    }
    float y2[4];
#pragma unroll
    for (int jo = 0; jo < 4; ++jo) {
        float a = sb[80 + jo];
#pragma unroll
        for (int k = 0; k < 16; ++k) a += sb[16 + jo * 16 + k] * fmaxf(y1[k], 0.0f);
        y2[jo] = fmaxf(a, 0.0f);
    }
    float y = sb[88];
#pragma unroll
    for (int k = 0; k < 4; ++k) y += sb[84 + k] * y2[k];

    y_bt[idx] = y;
}

// ------------------------------------------------------------- FD stencil ---
__global__ void deriv_k(const float* __restrict__ in,   // [64][3000]
                        float* __restrict__ outp)       // [64][3000]
{
    const int idx = blockIdx.x * blockDim.x + threadIdx.x;
    if (idx >= BATCH * T_STEPS) return;
    const int t = idx % T_STEPS;
    float v;
    if (t == 0) {
        v = (-1.5f * in[idx] + 2.0f * in[idx + 1] - 0.5f * in[idx + 2]) * INV_DT;
    } else if (t == T_STEPS - 1) {
        v = (0.5f * in[idx - 2] - 2.0f * in[idx - 1] + 1.5f * in[idx]) * INV_DT;
    } else {
        v = (in[idx + 1] - in[idx - 1]) * (0.5f * INV_DT);
    }
    outp[idx] = v;
}

// ------------------------------------------------------------------ launch --
extern "C" void kernel_launch(void* const* d_in, const int* in_sizes, int n_in,
                              void* d_out, int out_size, void* d_ws, size_t ws_size,
                              hipStream_t stream)
{
    const float* x     = (const float*)d_in[0];
    const float* w_ih0 = (const float*)d_in[1];
    const float* w_hh0 = (const float*)d_in[2];
    const float* b_ih0 = (const float*)d_in[3];
    const float* b_hh0 = (const float*)d_in[4];
    const float* w_ih1 = (const float*)d_in[5];
    const float* w_hh1 = (const float*)d_in[6];
    const float* b_ih1 = (const float*)d_in[7];
    const float* b_hh1 = (const float*)d_in[8];
    const float* fc1_w = (const float*)d_in[9];
    const float* fc1_b = (const float*)d_in[10];
    const float* fc2_w = (const float*)d_in[11];
    const float* fc2_b = (const float*)d_in[12];
    const float* fc3_w = (const float*)d_in[13];
    const float* fc3_b = (const float*)d_in[14];
    float* out = (float*)d_out;

    // ws layout: h buffer (98.304 MB) | y (0.768 MB) | z (0.768 MB)
    float* h_buf = (float*)d_ws;
    float* y_bt  = (float*)((char*)d_ws + 98304000);
    float* z_bt  = (float*)((char*)d_ws + 98304000 + 768000);

    lstm_layer0<<<dim3(BATCH), dim3(512), 0, stream>>>(x, w_ih0, w_hh0, b_ih0, b_hh0, h_buf);
    lstm_layer1<<<dim3(BATCH), dim3(512), 0, stream>>>(w_ih1, w_hh1, b_ih1, b_hh1, h_buf);

    const int nelem = T_STEPS * BATCH;   // 192000 = 750 * 256
    fc_head<<<dim3(nelem / 256), dim3(256), 0, stream>>>(
        h_buf, fc1_w, fc1_b, fc2_w, fc2_b, fc3_w, fc3_b, y_bt);
    deriv_k<<<dim3(nelem / 256), dim3(256), 0, stream>>>(y_bt, z_bt);
    deriv_k<<<dim3(nelem / 256), dim3(256), 0, stream>>>(z_bt, out);
}